// Round 4
// baseline (35.945 us; speedup 1.0000x reference)
//
#include <hip/hip_runtime.h>

#define L 3072
#define NT 512
#define CUT2 5.76f   // 2.4^2
#define GRID 1024
#define BLOCK 256

typedef unsigned int u32;
typedef unsigned long long u64;

// ---------------------------------------------------------------------------
// Prep: ONE block, 1024 threads, 3 atoms/thread. Wave-shuffle scans.
// Compacts columns (meta + 12 SoA coordinate planes at compact index) and
// rows. meta: a(12b) | tok<<12 (9b) | m0<<21 | m1<<22.
// hdr[0]=ncol hdr[1]=nrow. Also zeroes the ticket for this call.
// ---------------------------------------------------------------------------
__global__ __launch_bounds__(1024) void plbl_prep(
    const int* __restrict__ is_ligand,
    const int* __restrict__ tokmap,
    const int* __restrict__ crd,
    const float* __restrict__ X,
    const float* __restrict__ Xgt,
    u32* __restrict__ hdr,
    u32* __restrict__ ticket,
    u32* __restrict__ rowlist,
    u32* __restrict__ colmeta,
    float* __restrict__ planes)
{
    const int t = threadIdx.x;
    const int lane = t & 63;
    const int wv = t >> 6;
    __shared__ u32 s_wtot[2][16];

    u32 cc = 0, rc = 0;
    u32 meta[3];
    bool cok[3], rok[3];
    #pragma unroll
    for (int k = 0; k < 3; k++) {
        const int a = t * 3 + k;
        const int tok = tokmap[a];
        const int lig = is_ligand[tok];
        const u32 m0 = crd[a] != 0;
        const u32 m1 = crd[L + a] != 0;
        const bool any = (m0 | m1) != 0u;
        meta[k] = (u32)a | ((u32)tok << 12) | (m0 << 21) | (m1 << 22);
        cok[k] = (lig == 0) && any;
        rok[k] = (lig != 0) && any;
        cc += cok[k] ? 1u : 0u;
        rc += rok[k] ? 1u : 0u;
    }

    u32 ci = cc, ri = rc;
    #pragma unroll
    for (int o = 1; o < 64; o <<= 1) {
        u32 cv = __shfl_up(ci, o, 64);
        u32 rv = __shfl_up(ri, o, 64);
        if (lane >= o) { ci += cv; ri += rv; }
    }
    if (lane == 63) { s_wtot[0][wv] = ci; s_wtot[1][wv] = ri; }
    __syncthreads();

    if (wv == 0 && lane < 16) {
        const u32 c = s_wtot[0][lane];
        const u32 r = s_wtot[1][lane];
        u32 cs = c, rs = r;
        #pragma unroll
        for (int o = 1; o < 16; o <<= 1) {
            u32 cv = __shfl_up(cs, o, 64);
            u32 rv = __shfl_up(rs, o, 64);
            if (lane >= o) { cs += cv; rs += rv; }
        }
        s_wtot[0][lane] = cs - c;
        s_wtot[1][lane] = rs - r;
        if (lane == 15) { hdr[0] = cs; hdr[1] = rs; }
    }
    __syncthreads();

    u32 coff = s_wtot[0][wv] + (ci - cc);
    u32 roff = s_wtot[1][wv] + (ri - rc);
    #pragma unroll
    for (int k = 0; k < 3; k++) {
        if (cok[k]) {
            const int a = (int)(meta[k] & 0xFFF);
            const u32 w = coff++;
            colmeta[w] = meta[k];
            planes[0 * L + w]  = X[(0 * L + a) * 3 + 0];
            planes[1 * L + w]  = X[(0 * L + a) * 3 + 1];
            planes[2 * L + w]  = X[(0 * L + a) * 3 + 2];
            planes[3 * L + w]  = X[(1 * L + a) * 3 + 0];
            planes[4 * L + w]  = X[(1 * L + a) * 3 + 1];
            planes[5 * L + w]  = X[(1 * L + a) * 3 + 2];
            planes[6 * L + w]  = Xgt[(0 * L + a) * 3 + 0];
            planes[7 * L + w]  = Xgt[(0 * L + a) * 3 + 1];
            planes[8 * L + w]  = Xgt[(0 * L + a) * 3 + 2];
            planes[9 * L + w]  = Xgt[(1 * L + a) * 3 + 0];
            planes[10 * L + w] = Xgt[(1 * L + a) * 3 + 1];
            planes[11 * L + w] = Xgt[(1 * L + a) * 3 + 2];
        }
        if (rok[k]) rowlist[roff++] = meta[k];
    }

    if (t == 0) {
        __hip_atomic_store(ticket, 0u, __ATOMIC_RELAXED,
                           __HIP_MEMORY_SCOPE_AGENT);
    }
}

// ---------------------------------------------------------------------------
// Main: fixed GRID blocks, rows strided. Bond row packed to a 64B LDS
// bitmask per row. Inner loop: coalesced SoA plane loads, exec-masked on
// bond, branchless inside. Fused finalize via relaxed ticket (no acq/rel
// fences in the body — the R2 lesson).
// ---------------------------------------------------------------------------
__global__ __launch_bounds__(BLOCK) void plbl_main(
    const int* __restrict__ token_bonds,
    const float* __restrict__ X,
    const float* __restrict__ Xgt,
    const u32* __restrict__ hdr,
    u32* __restrict__ ticket,
    const u32* __restrict__ rowlist,
    const u32* __restrict__ colmeta,
    const float* __restrict__ planes,
    double* __restrict__ part_sum,
    u32* __restrict__ part_cnt,
    float* __restrict__ out)
{
    const int t = threadIdx.x;
    const int lane = t & 63;
    const int wv = t >> 6;
    const int ncol = (int)hdr[0];
    const int nrow = (int)hdr[1];

    __shared__ u64 s_bond[8];
    __shared__ double s_sum[BLOCK];
    __shared__ u32 s_cnt[BLOCK];
    __shared__ int s_last;

    const float* __restrict__ cx0 = planes + 0 * L;
    const float* __restrict__ cy0 = planes + 1 * L;
    const float* __restrict__ cz0 = planes + 2 * L;
    const float* __restrict__ cx1 = planes + 3 * L;
    const float* __restrict__ cy1 = planes + 4 * L;
    const float* __restrict__ cz1 = planes + 5 * L;
    const float* __restrict__ hx0 = planes + 6 * L;
    const float* __restrict__ hy0 = planes + 7 * L;
    const float* __restrict__ hz0 = planes + 8 * L;
    const float* __restrict__ hx1 = planes + 9 * L;
    const float* __restrict__ hy1 = planes + 10 * L;
    const float* __restrict__ hz1 = planes + 11 * L;

    double acc = 0.0;
    u32 cnt = 0;

    for (int rb = blockIdx.x; rb < nrow; rb += GRID) {
        const u32 rm = rowlist[rb];
        const int a1  = rm & 0xFFF;
        const u32 ta1 = (rm >> 12) & 0x1FF;
        const bool rm0 = (rm >> 21) & 1;
        const bool rm1 = (rm >> 22) & 1;

        // Pack bond row (512 ints) into a 64B LDS bitmask.
        const int* __restrict__ bondrow = token_bonds + ta1 * NT;
        const bool b0 = bondrow[t] != 0;
        const bool b1 = bondrow[t + 256] != 0;
        const u64 bal0 = __ballot(b0);
        const u64 bal1 = __ballot(b1);
        if (lane == 0) { s_bond[wv] = bal0; s_bond[4 + wv] = bal1; }
        __syncthreads();

        const float p0x = X[(0 * L + a1) * 3 + 0];
        const float p0y = X[(0 * L + a1) * 3 + 1];
        const float p0z = X[(0 * L + a1) * 3 + 2];
        const float p1x = X[(1 * L + a1) * 3 + 0];
        const float p1y = X[(1 * L + a1) * 3 + 1];
        const float p1z = X[(1 * L + a1) * 3 + 2];
        const float g0x = Xgt[(0 * L + a1) * 3 + 0];
        const float g0y = Xgt[(0 * L + a1) * 3 + 1];
        const float g0z = Xgt[(0 * L + a1) * 3 + 2];
        const float g1x = Xgt[(1 * L + a1) * 3 + 0];
        const float g1y = Xgt[(1 * L + a1) * 3 + 1];
        const float g1z = Xgt[(1 * L + a1) * 3 + 2];

        for (int j = t; j < ncol; j += BLOCK) {
            const u32 cm = colmeta[j];
            const u32 tok = (cm >> 12) & 0x1FF;
            if ((s_bond[tok >> 6] >> (tok & 63)) & 1ULL) {
                // batch 0
                const float dgx0 = g0x - hx0[j];
                const float dgy0 = g0y - hy0[j];
                const float dgz0 = g0z - hz0[j];
                const float gt2_0 = dgx0 * dgx0 + dgy0 * dgy0 + dgz0 * dgz0;
                const float dpx0 = p0x - cx0[j];
                const float dpy0 = p0y - cy0[j];
                const float dpz0 = p0z - cz0[j];
                const float pr2_0 = dpx0 * dpx0 + dpy0 * dpy0 + dpz0 * dpz0;
                const float d0 = sqrtf(pr2_0) - sqrtf(gt2_0);
                const bool k0 = rm0 && ((cm >> 21) & 1) && (gt2_0 < CUT2);
                // batch 1
                const float dgx1 = g1x - hx1[j];
                const float dgy1 = g1y - hy1[j];
                const float dgz1 = g1z - hz1[j];
                const float gt2_1 = dgx1 * dgx1 + dgy1 * dgy1 + dgz1 * dgz1;
                const float dpx1 = p1x - cx1[j];
                const float dpy1 = p1y - cy1[j];
                const float dpz1 = p1z - cz1[j];
                const float pr2_1 = dpx1 * dpx1 + dpy1 * dpy1 + dpz1 * dpz1;
                const float d1 = sqrtf(pr2_1) - sqrtf(gt2_1);
                const bool k1 = rm1 && ((cm >> 22) & 1) && (gt2_1 < CUT2);

                const float e = (k0 ? d0 * d0 : 0.0f) + (k1 ? d1 * d1 : 0.0f);
                acc += (double)e;
                cnt += (k0 ? 1u : 0u) + (k1 ? 1u : 0u);
            }
        }
        __syncthreads();   // protect s_bond before next row overwrites it
    }

    // Block reduction.
    s_sum[t] = acc;
    s_cnt[t] = cnt;
    __syncthreads();
    for (int sft = BLOCK / 2; sft > 0; sft >>= 1) {
        if (t < sft) {
            s_sum[t] += s_sum[t + sft];
            s_cnt[t] += s_cnt[t + sft];
        }
        __syncthreads();
    }

    // Partial out via coherent-point atomic stores (no fences), then ticket.
    if (t == 0) {
        __hip_atomic_store(&part_sum[blockIdx.x], s_sum[0], __ATOMIC_RELAXED,
                           __HIP_MEMORY_SCOPE_AGENT);
        __hip_atomic_store(&part_cnt[blockIdx.x], s_cnt[0], __ATOMIC_RELAXED,
                           __HIP_MEMORY_SCOPE_AGENT);
        asm volatile("s_waitcnt vmcnt(0)" ::: "memory");
        const u32 old = __hip_atomic_fetch_add(ticket, 1u, __ATOMIC_RELAXED,
                                               __HIP_MEMORY_SCOPE_AGENT);
        s_last = (old == (u32)(GRID - 1)) ? 1 : 0;
    }
    __syncthreads();
    if (!s_last) return;

    // Winner: deterministic reduce over all GRID partials.
    double a = 0.0;
    u32 c = 0;
    for (int i = t; i < GRID; i += BLOCK) {
        a += __hip_atomic_load(&part_sum[i], __ATOMIC_RELAXED,
                               __HIP_MEMORY_SCOPE_AGENT);
        c += __hip_atomic_load(&part_cnt[i], __ATOMIC_RELAXED,
                               __HIP_MEMORY_SCOPE_AGENT);
    }
    s_sum[t] = a;
    s_cnt[t] = c;
    __syncthreads();
    for (int sft = BLOCK / 2; sft > 0; sft >>= 1) {
        if (t < sft) {
            s_sum[t] += s_sum[t + sft];
            s_cnt[t] += s_cnt[t + sft];
        }
        __syncthreads();
    }
    if (t == 0) {
        const u32 n = s_cnt[0] ? s_cnt[0] : 1u;
        const float loss = (float)(s_sum[0] / (double)n);
        out[0] = loss;
        out[1] = loss;
    }
}

extern "C" void kernel_launch(void* const* d_in, const int* in_sizes, int n_in,
                              void* d_out, int out_size, void* d_ws, size_t ws_size,
                              hipStream_t stream) {
    const int*   is_ligand   = (const int*)d_in[0];
    const int*   token_bonds = (const int*)d_in[1];
    const int*   tokmap      = (const int*)d_in[2];
    const int*   crd_mask    = (const int*)d_in[3];
    const float* X           = (const float*)d_in[4];
    const float* Xgt         = (const float*)d_in[5];
    float* out = (float*)d_out;

    char* w = (char*)d_ws;
    u32*    hdr      = (u32*)(w + 0);
    u32*    ticket   = (u32*)(w + 128);
    u32*    rowlist  = (u32*)(w + 256);
    u32*    colmeta  = (u32*)(w + 256 + 4 * L);
    float*  planes   = (float*)(w + 256 + 8 * L);
    double* part_sum = (double*)(w + 256 + 8 * L + 48 * L);
    u32*    part_cnt = (u32*)(w + 256 + 8 * L + 48 * L + 8 * GRID);

    plbl_prep<<<1, 1024, 0, stream>>>(is_ligand, tokmap, crd_mask, X, Xgt,
                                      hdr, ticket, rowlist, colmeta, planes);
    plbl_main<<<GRID, BLOCK, 0, stream>>>(token_bonds, X, Xgt, hdr, ticket,
                                          rowlist, colmeta, planes,
                                          part_sum, part_cnt, out);
}

// Round 5
// 29.521 us; speedup vs baseline: 1.2176x; 1.2176x over previous
//
#include <hip/hip_runtime.h>

#define L 3072
#define NT 512
#define CUT2 5.76f   // 2.4^2
#define GRID 512
#define BLOCK 256

typedef unsigned int u32;
typedef unsigned long long u64;

// ---------------------------------------------------------------------------
// Prep: ONE block, 1024 threads, 3 atoms/thread. Wave-shuffle scans.
// Compacts columns (meta + 12 SoA coordinate planes at compact index) and
// rows. meta: a(12b) | tok<<12 (9b) | m0<<21 | m1<<22.
// hdr[0]=ncol hdr[1]=nrow. Also zeroes the ticket for this call.
// ---------------------------------------------------------------------------
__global__ __launch_bounds__(1024) void plbl_prep(
    const int* __restrict__ is_ligand,
    const int* __restrict__ tokmap,
    const int* __restrict__ crd,
    const float* __restrict__ X,
    const float* __restrict__ Xgt,
    u32* __restrict__ hdr,
    u32* __restrict__ ticket,
    u32* __restrict__ rowlist,
    u32* __restrict__ colmeta,
    float* __restrict__ planes)
{
    const int t = threadIdx.x;
    const int lane = t & 63;
    const int wv = t >> 6;
    __shared__ u32 s_wtot[2][16];

    u32 cc = 0, rc = 0;
    u32 meta[3];
    bool cok[3], rok[3];
    #pragma unroll
    for (int k = 0; k < 3; k++) {
        const int a = t * 3 + k;
        const int tok = tokmap[a];
        const int lig = is_ligand[tok];
        const u32 m0 = crd[a] != 0;
        const u32 m1 = crd[L + a] != 0;
        const bool any = (m0 | m1) != 0u;
        meta[k] = (u32)a | ((u32)tok << 12) | (m0 << 21) | (m1 << 22);
        cok[k] = (lig == 0) && any;
        rok[k] = (lig != 0) && any;
        cc += cok[k] ? 1u : 0u;
        rc += rok[k] ? 1u : 0u;
    }

    u32 ci = cc, ri = rc;
    #pragma unroll
    for (int o = 1; o < 64; o <<= 1) {
        u32 cv = __shfl_up(ci, o, 64);
        u32 rv = __shfl_up(ri, o, 64);
        if (lane >= o) { ci += cv; ri += rv; }
    }
    if (lane == 63) { s_wtot[0][wv] = ci; s_wtot[1][wv] = ri; }
    __syncthreads();

    if (wv == 0 && lane < 16) {
        const u32 c = s_wtot[0][lane];
        const u32 r = s_wtot[1][lane];
        u32 cs = c, rs = r;
        #pragma unroll
        for (int o = 1; o < 16; o <<= 1) {
            u32 cv = __shfl_up(cs, o, 64);
            u32 rv = __shfl_up(rs, o, 64);
            if (lane >= o) { cs += cv; rs += rv; }
        }
        s_wtot[0][lane] = cs - c;
        s_wtot[1][lane] = rs - r;
        if (lane == 15) { hdr[0] = cs; hdr[1] = rs; }
    }
    __syncthreads();

    u32 coff = s_wtot[0][wv] + (ci - cc);
    u32 roff = s_wtot[1][wv] + (ri - rc);
    #pragma unroll
    for (int k = 0; k < 3; k++) {
        if (cok[k]) {
            const int a = (int)(meta[k] & 0xFFF);
            const u32 w = coff++;
            colmeta[w] = meta[k];
            planes[0 * L + w]  = X[(0 * L + a) * 3 + 0];
            planes[1 * L + w]  = X[(0 * L + a) * 3 + 1];
            planes[2 * L + w]  = X[(0 * L + a) * 3 + 2];
            planes[3 * L + w]  = X[(1 * L + a) * 3 + 0];
            planes[4 * L + w]  = X[(1 * L + a) * 3 + 1];
            planes[5 * L + w]  = X[(1 * L + a) * 3 + 2];
            planes[6 * L + w]  = Xgt[(0 * L + a) * 3 + 0];
            planes[7 * L + w]  = Xgt[(0 * L + a) * 3 + 1];
            planes[8 * L + w]  = Xgt[(0 * L + a) * 3 + 2];
            planes[9 * L + w]  = Xgt[(1 * L + a) * 3 + 0];
            planes[10 * L + w] = Xgt[(1 * L + a) * 3 + 1];
            planes[11 * L + w] = Xgt[(1 * L + a) * 3 + 2];
        }
        if (rok[k]) rowlist[roff++] = meta[k];
    }

    if (t == 0) {
        __hip_atomic_store(ticket, 0u, __ATOMIC_RELAXED,
                           __HIP_MEMORY_SCOPE_AGENT);
    }
}

// ---------------------------------------------------------------------------
// Main: GRID blocks, rows strided (~2-3 rows/block). Bond row packed to a
// 64B LDS bitmask per row. Inner loop: ALL loads unconditional (addresses
// depend only on j) so iterations are independent and fully pipelined;
// masks only predicate the accumulate. Fused finalize via small relaxed
// ticket (GRID-wide, not per-row).
// ---------------------------------------------------------------------------
__global__ __launch_bounds__(BLOCK) void plbl_main(
    const int* __restrict__ token_bonds,
    const float* __restrict__ X,
    const float* __restrict__ Xgt,
    const u32* __restrict__ hdr,
    u32* __restrict__ ticket,
    const u32* __restrict__ rowlist,
    const u32* __restrict__ colmeta,
    const float* __restrict__ planes,
    double* __restrict__ part_sum,
    u32* __restrict__ part_cnt,
    float* __restrict__ out)
{
    const int t = threadIdx.x;
    const int lane = t & 63;
    const int wv = t >> 6;
    const int ncol = (int)hdr[0];
    const int nrow = (int)hdr[1];

    __shared__ u64 s_bond[8];
    __shared__ double s_sum[BLOCK];
    __shared__ u32 s_cnt[BLOCK];
    __shared__ int s_last;

    const float* __restrict__ cx0 = planes + 0 * L;
    const float* __restrict__ cy0 = planes + 1 * L;
    const float* __restrict__ cz0 = planes + 2 * L;
    const float* __restrict__ cx1 = planes + 3 * L;
    const float* __restrict__ cy1 = planes + 4 * L;
    const float* __restrict__ cz1 = planes + 5 * L;
    const float* __restrict__ hx0 = planes + 6 * L;
    const float* __restrict__ hy0 = planes + 7 * L;
    const float* __restrict__ hz0 = planes + 8 * L;
    const float* __restrict__ hx1 = planes + 9 * L;
    const float* __restrict__ hy1 = planes + 10 * L;
    const float* __restrict__ hz1 = planes + 11 * L;

    double acc = 0.0;
    u32 cnt = 0;

    for (int rb = blockIdx.x; rb < nrow; rb += GRID) {
        const u32 rm = rowlist[rb];
        const int a1  = rm & 0xFFF;
        const u32 ta1 = (rm >> 12) & 0x1FF;
        const u32 rbits = (rm >> 21) & 3u;   // m0 | m1<<1

        // Pack bond row (512 ints) into a 64B LDS bitmask.
        const int* __restrict__ bondrow = token_bonds + ta1 * NT;
        const bool b0 = bondrow[t] != 0;
        const bool b1 = bondrow[t + 256] != 0;
        const u64 bal0 = __ballot(b0);
        const u64 bal1 = __ballot(b1);
        if (lane == 0) { s_bond[wv] = bal0; s_bond[4 + wv] = bal1; }
        __syncthreads();

        const float p0x = X[(0 * L + a1) * 3 + 0];
        const float p0y = X[(0 * L + a1) * 3 + 1];
        const float p0z = X[(0 * L + a1) * 3 + 2];
        const float p1x = X[(1 * L + a1) * 3 + 0];
        const float p1y = X[(1 * L + a1) * 3 + 1];
        const float p1z = X[(1 * L + a1) * 3 + 2];
        const float g0x = Xgt[(0 * L + a1) * 3 + 0];
        const float g0y = Xgt[(0 * L + a1) * 3 + 1];
        const float g0z = Xgt[(0 * L + a1) * 3 + 2];
        const float g1x = Xgt[(1 * L + a1) * 3 + 0];
        const float g1y = Xgt[(1 * L + a1) * 3 + 1];
        const float g1z = Xgt[(1 * L + a1) * 3 + 2];

        for (int j = t; j < ncol; j += BLOCK) {
            // All loads unconditional — no dependence on cm, full pipelining.
            const u32 cm = colmeta[j];
            const float vx0 = cx0[j], vy0 = cy0[j], vz0 = cz0[j];
            const float vx1 = cx1[j], vy1 = cy1[j], vz1 = cz1[j];
            const float wx0 = hx0[j], wy0 = hy0[j], wz0 = hz0[j];
            const float wx1 = hx1[j], wy1 = hy1[j], wz1 = hz1[j];

            const u32 tok = (cm >> 12) & 0x1FF;
            const bool bond = (s_bond[tok >> 6] >> (tok & 63)) & 1ULL;

            // batch 0
            const float dgx0 = g0x - wx0, dgy0 = g0y - wy0, dgz0 = g0z - wz0;
            const float gt2_0 = dgx0 * dgx0 + dgy0 * dgy0 + dgz0 * dgz0;
            const float dpx0 = p0x - vx0, dpy0 = p0y - vy0, dpz0 = p0z - vz0;
            const float pr2_0 = dpx0 * dpx0 + dpy0 * dpy0 + dpz0 * dpz0;
            const float d0 = sqrtf(pr2_0) - sqrtf(gt2_0);
            const bool k0 = bond && (rbits & 1u) && ((cm >> 21) & 1u) && (gt2_0 < CUT2);
            // batch 1
            const float dgx1 = g1x - wx1, dgy1 = g1y - wy1, dgz1 = g1z - wz1;
            const float gt2_1 = dgx1 * dgx1 + dgy1 * dgy1 + dgz1 * dgz1;
            const float dpx1 = p1x - vx1, dpy1 = p1y - vy1, dpz1 = p1z - vz1;
            const float pr2_1 = dpx1 * dpx1 + dpy1 * dpy1 + dpz1 * dpz1;
            const float d1 = sqrtf(pr2_1) - sqrtf(gt2_1);
            const bool k1 = bond && (rbits & 2u) && ((cm >> 22) & 1u) && (gt2_1 < CUT2);

            const float e = (k0 ? d0 * d0 : 0.0f) + (k1 ? d1 * d1 : 0.0f);
            acc += (double)e;
            cnt += (k0 ? 1u : 0u) + (k1 ? 1u : 0u);
        }
        __syncthreads();   // protect s_bond before next row overwrites it
    }

    // Block reduction.
    s_sum[t] = acc;
    s_cnt[t] = cnt;
    __syncthreads();
    for (int sft = BLOCK / 2; sft > 0; sft >>= 1) {
        if (t < sft) {
            s_sum[t] += s_sum[t + sft];
            s_cnt[t] += s_cnt[t + sft];
        }
        __syncthreads();
    }

    // Partial out via coherent-point stores (no fences), then small ticket.
    if (t == 0) {
        __hip_atomic_store(&part_sum[blockIdx.x], s_sum[0], __ATOMIC_RELAXED,
                           __HIP_MEMORY_SCOPE_AGENT);
        __hip_atomic_store(&part_cnt[blockIdx.x], s_cnt[0], __ATOMIC_RELAXED,
                           __HIP_MEMORY_SCOPE_AGENT);
        asm volatile("s_waitcnt vmcnt(0)" ::: "memory");
        const u32 old = __hip_atomic_fetch_add(ticket, 1u, __ATOMIC_RELAXED,
                                               __HIP_MEMORY_SCOPE_AGENT);
        s_last = (old == (u32)(GRID - 1)) ? 1 : 0;
    }
    __syncthreads();
    if (!s_last) return;

    // Winner: deterministic reduce over GRID partials (2 iters per thread).
    double a = 0.0;
    u32 c = 0;
    for (int i = t; i < GRID; i += BLOCK) {
        a += __hip_atomic_load(&part_sum[i], __ATOMIC_RELAXED,
                               __HIP_MEMORY_SCOPE_AGENT);
        c += __hip_atomic_load(&part_cnt[i], __ATOMIC_RELAXED,
                               __HIP_MEMORY_SCOPE_AGENT);
    }
    s_sum[t] = a;
    s_cnt[t] = c;
    __syncthreads();
    for (int sft = BLOCK / 2; sft > 0; sft >>= 1) {
        if (t < sft) {
            s_sum[t] += s_sum[t + sft];
            s_cnt[t] += s_cnt[t + sft];
        }
        __syncthreads();
    }
    if (t == 0) {
        const u32 n = s_cnt[0] ? s_cnt[0] : 1u;
        const float loss = (float)(s_sum[0] / (double)n);
        out[0] = loss;
        out[1] = loss;
    }
}

extern "C" void kernel_launch(void* const* d_in, const int* in_sizes, int n_in,
                              void* d_out, int out_size, void* d_ws, size_t ws_size,
                              hipStream_t stream) {
    const int*   is_ligand   = (const int*)d_in[0];
    const int*   token_bonds = (const int*)d_in[1];
    const int*   tokmap      = (const int*)d_in[2];
    const int*   crd_mask    = (const int*)d_in[3];
    const float* X           = (const float*)d_in[4];
    const float* Xgt         = (const float*)d_in[5];
    float* out = (float*)d_out;

    char* w = (char*)d_ws;
    u32*    hdr      = (u32*)(w + 0);
    u32*    ticket   = (u32*)(w + 128);
    u32*    rowlist  = (u32*)(w + 256);
    u32*    colmeta  = (u32*)(w + 256 + 4 * L);
    float*  planes   = (float*)(w + 256 + 8 * L);
    double* part_sum = (double*)(w + 256 + 8 * L + 48 * L);
    u32*    part_cnt = (u32*)(w + 256 + 8 * L + 48 * L + 8 * GRID);

    plbl_prep<<<1, 1024, 0, stream>>>(is_ligand, tokmap, crd_mask, X, Xgt,
                                      hdr, ticket, rowlist, colmeta, planes);
    plbl_main<<<GRID, BLOCK, 0, stream>>>(token_bonds, X, Xgt, hdr, ticket,
                                          rowlist, colmeta, planes,
                                          part_sum, part_cnt, out);
}

// Round 6
// 25.024 us; speedup vs baseline: 1.4364x; 1.1797x over previous
//
#include <hip/hip_runtime.h>

#define L 3072
#define NT 512
#define CUT2 5.76f   // 2.4^2
#define GRID 1024
#define BLOCK 256

typedef unsigned int u32;
typedef unsigned long long u64;

// ---------------------------------------------------------------------------
// Prep: ONE block, 1024 threads, 3 atoms/thread. Wave-shuffle scans.
// Compacts columns (meta + 12 SoA coordinate planes at compact index) and
// rows. meta: a(12b) | tok<<12 (9b) | m0<<21 | m1<<22.
// hdr[0]=ncol hdr[1]=nrow.
// ---------------------------------------------------------------------------
__global__ __launch_bounds__(1024) void plbl_prep(
    const int* __restrict__ is_ligand,
    const int* __restrict__ tokmap,
    const int* __restrict__ crd,
    const float* __restrict__ X,
    const float* __restrict__ Xgt,
    u32* __restrict__ hdr,
    u32* __restrict__ rowlist,
    u32* __restrict__ colmeta,
    float* __restrict__ planes)
{
    const int t = threadIdx.x;
    const int lane = t & 63;
    const int wv = t >> 6;
    __shared__ u32 s_wtot[2][16];

    u32 cc = 0, rc = 0;
    u32 meta[3];
    bool cok[3], rok[3];
    #pragma unroll
    for (int k = 0; k < 3; k++) {
        const int a = t * 3 + k;
        const int tok = tokmap[a];
        const int lig = is_ligand[tok];
        const u32 m0 = crd[a] != 0;
        const u32 m1 = crd[L + a] != 0;
        const bool any = (m0 | m1) != 0u;
        meta[k] = (u32)a | ((u32)tok << 12) | (m0 << 21) | (m1 << 22);
        cok[k] = (lig == 0) && any;
        rok[k] = (lig != 0) && any;
        cc += cok[k] ? 1u : 0u;
        rc += rok[k] ? 1u : 0u;
    }

    u32 ci = cc, ri = rc;
    #pragma unroll
    for (int o = 1; o < 64; o <<= 1) {
        u32 cv = __shfl_up(ci, o, 64);
        u32 rv = __shfl_up(ri, o, 64);
        if (lane >= o) { ci += cv; ri += rv; }
    }
    if (lane == 63) { s_wtot[0][wv] = ci; s_wtot[1][wv] = ri; }
    __syncthreads();

    if (wv == 0 && lane < 16) {
        const u32 c = s_wtot[0][lane];
        const u32 r = s_wtot[1][lane];
        u32 cs = c, rs = r;
        #pragma unroll
        for (int o = 1; o < 16; o <<= 1) {
            u32 cv = __shfl_up(cs, o, 64);
            u32 rv = __shfl_up(rs, o, 64);
            if (lane >= o) { cs += cv; rs += rv; }
        }
        s_wtot[0][lane] = cs - c;
        s_wtot[1][lane] = rs - r;
        if (lane == 15) { hdr[0] = cs; hdr[1] = rs; }
    }
    __syncthreads();

    u32 coff = s_wtot[0][wv] + (ci - cc);
    u32 roff = s_wtot[1][wv] + (ri - rc);
    #pragma unroll
    for (int k = 0; k < 3; k++) {
        if (cok[k]) {
            const int a = (int)(meta[k] & 0xFFF);
            const u32 w = coff++;
            colmeta[w] = meta[k];
            planes[0 * L + w]  = X[(0 * L + a) * 3 + 0];
            planes[1 * L + w]  = X[(0 * L + a) * 3 + 1];
            planes[2 * L + w]  = X[(0 * L + a) * 3 + 2];
            planes[3 * L + w]  = X[(1 * L + a) * 3 + 0];
            planes[4 * L + w]  = X[(1 * L + a) * 3 + 1];
            planes[5 * L + w]  = X[(1 * L + a) * 3 + 2];
            planes[6 * L + w]  = Xgt[(0 * L + a) * 3 + 0];
            planes[7 * L + w]  = Xgt[(0 * L + a) * 3 + 1];
            planes[8 * L + w]  = Xgt[(0 * L + a) * 3 + 2];
            planes[9 * L + w]  = Xgt[(1 * L + a) * 3 + 0];
            planes[10 * L + w] = Xgt[(1 * L + a) * 3 + 1];
            planes[11 * L + w] = Xgt[(1 * L + a) * 3 + 2];
        }
        if (rok[k]) rowlist[roff++] = meta[k];
    }
}

// ---------------------------------------------------------------------------
// Main: GRID blocks, rows strided. Bond row packed to a 64B LDS bitmask per
// row. Inner loop: ALL loads unconditional (addresses depend only on j) so
// iterations pipeline fully; masks only predicate the accumulate. Plain
// partial stores — NO atomics, NO ticket (R4/R5 lesson: ticket costs ~10µs).
// Every block writes its partial (fixed grid ⇒ poison-safe).
// ---------------------------------------------------------------------------
__global__ __launch_bounds__(BLOCK) void plbl_main(
    const int* __restrict__ token_bonds,
    const float* __restrict__ X,
    const float* __restrict__ Xgt,
    const u32* __restrict__ hdr,
    const u32* __restrict__ rowlist,
    const u32* __restrict__ colmeta,
    const float* __restrict__ planes,
    double* __restrict__ part_sum,
    u32* __restrict__ part_cnt)
{
    const int t = threadIdx.x;
    const int lane = t & 63;
    const int wv = t >> 6;
    const int ncol = (int)hdr[0];
    const int nrow = (int)hdr[1];

    __shared__ u64 s_bond[8];
    __shared__ double s_sum[4];
    __shared__ u32 s_cnt[4];

    const float* __restrict__ cx0 = planes + 0 * L;
    const float* __restrict__ cy0 = planes + 1 * L;
    const float* __restrict__ cz0 = planes + 2 * L;
    const float* __restrict__ cx1 = planes + 3 * L;
    const float* __restrict__ cy1 = planes + 4 * L;
    const float* __restrict__ cz1 = planes + 5 * L;
    const float* __restrict__ hx0 = planes + 6 * L;
    const float* __restrict__ hy0 = planes + 7 * L;
    const float* __restrict__ hz0 = planes + 8 * L;
    const float* __restrict__ hx1 = planes + 9 * L;
    const float* __restrict__ hy1 = planes + 10 * L;
    const float* __restrict__ hz1 = planes + 11 * L;

    double acc = 0.0;
    u32 cnt = 0;

    for (int rb = blockIdx.x; rb < nrow; rb += GRID) {
        const u32 rm = rowlist[rb];
        const int a1  = rm & 0xFFF;
        const u32 ta1 = (rm >> 12) & 0x1FF;
        const u32 rbits = (rm >> 21) & 3u;   // m0 | m1<<1

        // Pack bond row (512 ints) into a 64B LDS bitmask.
        const int* __restrict__ bondrow = token_bonds + ta1 * NT;
        const bool b0 = bondrow[t] != 0;
        const bool b1 = bondrow[t + 256] != 0;
        const u64 bal0 = __ballot(b0);
        const u64 bal1 = __ballot(b1);
        if (lane == 0) { s_bond[wv] = bal0; s_bond[4 + wv] = bal1; }
        __syncthreads();

        const float p0x = X[(0 * L + a1) * 3 + 0];
        const float p0y = X[(0 * L + a1) * 3 + 1];
        const float p0z = X[(0 * L + a1) * 3 + 2];
        const float p1x = X[(1 * L + a1) * 3 + 0];
        const float p1y = X[(1 * L + a1) * 3 + 1];
        const float p1z = X[(1 * L + a1) * 3 + 2];
        const float g0x = Xgt[(0 * L + a1) * 3 + 0];
        const float g0y = Xgt[(0 * L + a1) * 3 + 1];
        const float g0z = Xgt[(0 * L + a1) * 3 + 2];
        const float g1x = Xgt[(1 * L + a1) * 3 + 0];
        const float g1y = Xgt[(1 * L + a1) * 3 + 1];
        const float g1z = Xgt[(1 * L + a1) * 3 + 2];

        for (int j = t; j < ncol; j += BLOCK) {
            const u32 cm = colmeta[j];
            const float vx0 = cx0[j], vy0 = cy0[j], vz0 = cz0[j];
            const float vx1 = cx1[j], vy1 = cy1[j], vz1 = cz1[j];
            const float wx0 = hx0[j], wy0 = hy0[j], wz0 = hz0[j];
            const float wx1 = hx1[j], wy1 = hy1[j], wz1 = hz1[j];

            const u32 tok = (cm >> 12) & 0x1FF;
            const bool bond = (s_bond[tok >> 6] >> (tok & 63)) & 1ULL;

            // batch 0
            const float dgx0 = g0x - wx0, dgy0 = g0y - wy0, dgz0 = g0z - wz0;
            const float gt2_0 = dgx0 * dgx0 + dgy0 * dgy0 + dgz0 * dgz0;
            const float dpx0 = p0x - vx0, dpy0 = p0y - vy0, dpz0 = p0z - vz0;
            const float pr2_0 = dpx0 * dpx0 + dpy0 * dpy0 + dpz0 * dpz0;
            const float d0 = sqrtf(pr2_0) - sqrtf(gt2_0);
            const bool k0 = bond && (rbits & 1u) && ((cm >> 21) & 1u) && (gt2_0 < CUT2);
            // batch 1
            const float dgx1 = g1x - wx1, dgy1 = g1y - wy1, dgz1 = g1z - wz1;
            const float gt2_1 = dgx1 * dgx1 + dgy1 * dgy1 + dgz1 * dgz1;
            const float dpx1 = p1x - vx1, dpy1 = p1y - vy1, dpz1 = p1z - vz1;
            const float pr2_1 = dpx1 * dpx1 + dpy1 * dpy1 + dpz1 * dpz1;
            const float d1 = sqrtf(pr2_1) - sqrtf(gt2_1);
            const bool k1 = bond && (rbits & 2u) && ((cm >> 22) & 1u) && (gt2_1 < CUT2);

            const float e = (k0 ? d0 * d0 : 0.0f) + (k1 ? d1 * d1 : 0.0f);
            acc += (double)e;
            cnt += (k0 ? 1u : 0u) + (k1 ? 1u : 0u);
        }
        __syncthreads();   // protect s_bond before next row overwrites it
    }

    // Wave shuffle reduce, then 4 wave partials through LDS.
    #pragma unroll
    for (int o = 32; o > 0; o >>= 1) {
        acc += __shfl_down(acc, o, 64);
        cnt += __shfl_down(cnt, o, 64);
    }
    if (lane == 0) { s_sum[wv] = acc; s_cnt[wv] = cnt; }
    __syncthreads();
    if (t == 0) {
        double a = s_sum[0] + s_sum[1] + s_sum[2] + s_sum[3];
        u32 c = s_cnt[0] + s_cnt[1] + s_cnt[2] + s_cnt[3];
        part_sum[blockIdx.x] = a;
        part_cnt[blockIdx.x] = c;
    }
}

// ---------------------------------------------------------------------------
// Finalize: one block, deterministic reduction over GRID partials.
// ---------------------------------------------------------------------------
__global__ __launch_bounds__(BLOCK) void plbl_fin(
    const double* __restrict__ part_sum,
    const u32* __restrict__ part_cnt,
    float* __restrict__ out)
{
    const int t = threadIdx.x;
    const int lane = t & 63;
    const int wv = t >> 6;
    double a = 0.0;
    u32 c = 0;
    #pragma unroll
    for (int i = 0; i < GRID / BLOCK; i++) {
        a += part_sum[t + i * BLOCK];
        c += part_cnt[t + i * BLOCK];
    }
    #pragma unroll
    for (int o = 32; o > 0; o >>= 1) {
        a += __shfl_down(a, o, 64);
        c += __shfl_down(c, o, 64);
    }
    __shared__ double s_sum[4];
    __shared__ u32 s_cnt[4];
    if (lane == 0) { s_sum[wv] = a; s_cnt[wv] = c; }
    __syncthreads();
    if (t == 0) {
        const double sum = s_sum[0] + s_sum[1] + s_sum[2] + s_sum[3];
        const u32 cc = s_cnt[0] + s_cnt[1] + s_cnt[2] + s_cnt[3];
        const u32 n = cc ? cc : 1u;
        const float loss = (float)(sum / (double)n);
        out[0] = loss;
        out[1] = loss;
    }
}

extern "C" void kernel_launch(void* const* d_in, const int* in_sizes, int n_in,
                              void* d_out, int out_size, void* d_ws, size_t ws_size,
                              hipStream_t stream) {
    const int*   is_ligand   = (const int*)d_in[0];
    const int*   token_bonds = (const int*)d_in[1];
    const int*   tokmap      = (const int*)d_in[2];
    const int*   crd_mask    = (const int*)d_in[3];
    const float* X           = (const float*)d_in[4];
    const float* Xgt         = (const float*)d_in[5];
    float* out = (float*)d_out;

    char* w = (char*)d_ws;
    u32*    hdr      = (u32*)(w + 0);
    u32*    rowlist  = (u32*)(w + 256);
    u32*    colmeta  = (u32*)(w + 256 + 4 * L);
    float*  planes   = (float*)(w + 256 + 8 * L);
    double* part_sum = (double*)(w + 256 + 8 * L + 48 * L);
    u32*    part_cnt = (u32*)(w + 256 + 8 * L + 48 * L + 8 * GRID);

    plbl_prep<<<1, 1024, 0, stream>>>(is_ligand, tokmap, crd_mask, X, Xgt,
                                      hdr, rowlist, colmeta, planes);
    plbl_main<<<GRID, BLOCK, 0, stream>>>(token_bonds, X, Xgt, hdr,
                                          rowlist, colmeta, planes,
                                          part_sum, part_cnt);
    plbl_fin<<<1, BLOCK, 0, stream>>>(part_sum, part_cnt, out);
}

// Round 7
// 20.232 us; speedup vs baseline: 1.7767x; 1.2369x over previous
//
#include <hip/hip_runtime.h>

#define L 3072
#define NT 512
#define CUT2 5.76f   // 2.4^2
#define GRID 256
#define BLOCK 1024

typedef unsigned int u32;
typedef unsigned long long u64;

// ---------------------------------------------------------------------------
// Main: 256 blocks x 1024 threads. Each block REDUNDANTLY compacts the
// column/row lists into its own LDS (deterministic, ~0.5us, parallel across
// blocks) -- no prep kernel, no global intermediates. Then rows strided
// across blocks; per row a 64B LDS bond bitmask; inner loop over compacted
// columns with unconditional loads and predicated accumulate.
// ---------------------------------------------------------------------------
__global__ __launch_bounds__(BLOCK) void plbl_main(
    const int* __restrict__ is_ligand,
    const int* __restrict__ token_bonds,
    const int* __restrict__ tokmap,
    const int* __restrict__ crd,
    const float* __restrict__ X,
    const float* __restrict__ Xgt,
    double* __restrict__ part_sum,
    u32* __restrict__ part_cnt)
{
    const int t = threadIdx.x;
    const int lane = t & 63;
    const int wv = t >> 6;

    __shared__ u32 s_wtot[2][16];
    __shared__ u32 s_colmeta[3072];   // ncol+nrow <= 3072 (disjoint), safe
    __shared__ u32 s_rowlist[3072];
    __shared__ u32 s_cnts[2];         // [0]=ncol [1]=nrow
    __shared__ u64 s_bond[8];
    __shared__ double s_rsum[16];
    __shared__ u32 s_rcnt[16];

    // ---------------- Phase A: in-LDS compaction (redundant per block) ----
    u32 cc = 0, rc = 0;
    u32 meta[3];
    bool cok[3], rok[3];
    #pragma unroll
    for (int k = 0; k < 3; k++) {
        const int a = t * 3 + k;
        const int tok = tokmap[a];
        const int lig = is_ligand[tok];
        const u32 m0 = crd[a] != 0;
        const u32 m1 = crd[L + a] != 0;
        const bool any = (m0 | m1) != 0u;
        meta[k] = (u32)a | ((u32)tok << 12) | (m0 << 21) | (m1 << 22);
        cok[k] = (lig == 0) && any;
        rok[k] = (lig != 0) && any;
        cc += cok[k] ? 1u : 0u;
        rc += rok[k] ? 1u : 0u;
    }

    u32 ci = cc, ri = rc;
    #pragma unroll
    for (int o = 1; o < 64; o <<= 1) {
        u32 cv = __shfl_up(ci, o, 64);
        u32 rv = __shfl_up(ri, o, 64);
        if (lane >= o) { ci += cv; ri += rv; }
    }
    if (lane == 63) { s_wtot[0][wv] = ci; s_wtot[1][wv] = ri; }
    __syncthreads();

    if (wv == 0 && lane < 16) {
        const u32 c = s_wtot[0][lane];
        const u32 r = s_wtot[1][lane];
        u32 cs = c, rs = r;
        #pragma unroll
        for (int o = 1; o < 16; o <<= 1) {
            u32 cv = __shfl_up(cs, o, 64);
            u32 rv = __shfl_up(rs, o, 64);
            if (lane >= o) { cs += cv; rs += rv; }
        }
        s_wtot[0][lane] = cs - c;
        s_wtot[1][lane] = rs - r;
        if (lane == 15) { s_cnts[0] = cs; s_cnts[1] = rs; }
    }
    __syncthreads();

    u32 coff = s_wtot[0][wv] + (ci - cc);
    u32 roff = s_wtot[1][wv] + (ri - rc);
    #pragma unroll
    for (int k = 0; k < 3; k++) {
        if (cok[k]) s_colmeta[coff++] = meta[k];
        if (rok[k]) s_rowlist[roff++] = meta[k];
    }
    __syncthreads();

    const int ncol = (int)s_cnts[0];
    const int nrow = (int)s_cnts[1];

    // ---------------- Phase B: rows strided across blocks -----------------
    double acc = 0.0;
    u32 cnt = 0;

    for (int rb = blockIdx.x; rb < nrow; rb += GRID) {
        const u32 rm = s_rowlist[rb];
        const int a1  = rm & 0xFFF;
        const u32 ta1 = (rm >> 12) & 0x1FF;
        const u32 rbits = (rm >> 21) & 3u;   // m0 | m1<<1

        // Bond row (512 ints) -> 64B LDS bitmask (waves 0..7 only).
        if (t < 512) {
            const bool bv = token_bonds[ta1 * NT + t] != 0;
            const u64 bal = __ballot(bv);
            if (lane == 0) s_bond[wv] = bal;
        }
        __syncthreads();

        const float p0x = X[(0 * L + a1) * 3 + 0];
        const float p0y = X[(0 * L + a1) * 3 + 1];
        const float p0z = X[(0 * L + a1) * 3 + 2];
        const float p1x = X[(1 * L + a1) * 3 + 0];
        const float p1y = X[(1 * L + a1) * 3 + 1];
        const float p1z = X[(1 * L + a1) * 3 + 2];
        const float g0x = Xgt[(0 * L + a1) * 3 + 0];
        const float g0y = Xgt[(0 * L + a1) * 3 + 1];
        const float g0z = Xgt[(0 * L + a1) * 3 + 2];
        const float g1x = Xgt[(1 * L + a1) * 3 + 0];
        const float g1y = Xgt[(1 * L + a1) * 3 + 1];
        const float g1z = Xgt[(1 * L + a1) * 3 + 2];

        for (int j = t; j < ncol; j += BLOCK) {
            const u32 cm = s_colmeta[j];
            const int a2 = (int)(cm & 0xFFF);
            const u32 tok = (cm >> 12) & 0x1FF;
            const bool bond = (s_bond[tok >> 6] >> (tok & 63)) & 1ULL;

            const int b0 = 3 * a2;            // batch0 coord base
            const int b1 = 3 * L + 3 * a2;    // batch1 coord base
            const float vx0 = X[b0 + 0], vy0 = X[b0 + 1], vz0 = X[b0 + 2];
            const float vx1 = X[b1 + 0], vy1 = X[b1 + 1], vz1 = X[b1 + 2];
            const float wx0 = Xgt[b0 + 0], wy0 = Xgt[b0 + 1], wz0 = Xgt[b0 + 2];
            const float wx1 = Xgt[b1 + 0], wy1 = Xgt[b1 + 1], wz1 = Xgt[b1 + 2];

            // batch 0
            const float dgx0 = g0x - wx0, dgy0 = g0y - wy0, dgz0 = g0z - wz0;
            const float gt2_0 = dgx0 * dgx0 + dgy0 * dgy0 + dgz0 * dgz0;
            const float dpx0 = p0x - vx0, dpy0 = p0y - vy0, dpz0 = p0z - vz0;
            const float pr2_0 = dpx0 * dpx0 + dpy0 * dpy0 + dpz0 * dpz0;
            const float d0 = sqrtf(pr2_0) - sqrtf(gt2_0);
            const bool k0 = bond && (rbits & 1u) && ((cm >> 21) & 1u) && (gt2_0 < CUT2);
            // batch 1
            const float dgx1 = g1x - wx1, dgy1 = g1y - wy1, dgz1 = g1z - wz1;
            const float gt2_1 = dgx1 * dgx1 + dgy1 * dgy1 + dgz1 * dgz1;
            const float dpx1 = p1x - vx1, dpy1 = p1y - vy1, dpz1 = p1z - vz1;
            const float pr2_1 = dpx1 * dpx1 + dpy1 * dpy1 + dpz1 * dpz1;
            const float d1 = sqrtf(pr2_1) - sqrtf(gt2_1);
            const bool k1 = bond && (rbits & 2u) && ((cm >> 22) & 1u) && (gt2_1 < CUT2);

            const float e = (k0 ? d0 * d0 : 0.0f) + (k1 ? d1 * d1 : 0.0f);
            acc += (double)e;
            cnt += (k0 ? 1u : 0u) + (k1 ? 1u : 0u);
        }
        __syncthreads();   // protect s_bond before next row overwrites it
    }

    // ---------------- Block reduction (16 waves) --------------------------
    #pragma unroll
    for (int o = 32; o > 0; o >>= 1) {
        acc += __shfl_down(acc, o, 64);
        cnt += __shfl_down(cnt, o, 64);
    }
    if (lane == 0) { s_rsum[wv] = acc; s_rcnt[wv] = cnt; }
    __syncthreads();
    if (t == 0) {
        double a = 0.0;
        u32 c = 0;
        #pragma unroll
        for (int i = 0; i < 16; i++) { a += s_rsum[i]; c += s_rcnt[i]; }
        part_sum[blockIdx.x] = a;
        part_cnt[blockIdx.x] = c;
    }
}

// ---------------------------------------------------------------------------
// Finalize: one block, deterministic reduction over GRID partials.
// ---------------------------------------------------------------------------
__global__ __launch_bounds__(256) void plbl_fin(
    const double* __restrict__ part_sum,
    const u32* __restrict__ part_cnt,
    float* __restrict__ out)
{
    const int t = threadIdx.x;
    const int lane = t & 63;
    const int wv = t >> 6;
    double a = part_sum[t];
    u32 c = part_cnt[t];
    #pragma unroll
    for (int o = 32; o > 0; o >>= 1) {
        a += __shfl_down(a, o, 64);
        c += __shfl_down(c, o, 64);
    }
    __shared__ double s_sum[4];
    __shared__ u32 s_cnt[4];
    if (lane == 0) { s_sum[wv] = a; s_cnt[wv] = c; }
    __syncthreads();
    if (t == 0) {
        const double sum = s_sum[0] + s_sum[1] + s_sum[2] + s_sum[3];
        const u32 cc = s_cnt[0] + s_cnt[1] + s_cnt[2] + s_cnt[3];
        const u32 n = cc ? cc : 1u;
        const float loss = (float)(sum / (double)n);
        out[0] = loss;
        out[1] = loss;
    }
}

extern "C" void kernel_launch(void* const* d_in, const int* in_sizes, int n_in,
                              void* d_out, int out_size, void* d_ws, size_t ws_size,
                              hipStream_t stream) {
    const int*   is_ligand   = (const int*)d_in[0];
    const int*   token_bonds = (const int*)d_in[1];
    const int*   tokmap      = (const int*)d_in[2];
    const int*   crd_mask    = (const int*)d_in[3];
    const float* X           = (const float*)d_in[4];
    const float* Xgt         = (const float*)d_in[5];
    float* out = (float*)d_out;

    char* w = (char*)d_ws;
    double* part_sum = (double*)(w + 0);
    u32*    part_cnt = (u32*)(w + 8 * GRID);

    plbl_main<<<GRID, BLOCK, 0, stream>>>(is_ligand, token_bonds, tokmap,
                                          crd_mask, X, Xgt,
                                          part_sum, part_cnt);
    plbl_fin<<<1, 256, 0, stream>>>(part_sum, part_cnt, out);
}

// Round 8
// 18.653 us; speedup vs baseline: 1.9271x; 1.0846x over previous
//
#include <hip/hip_runtime.h>

#define L 3072
#define NT 512
#define CUT2 5.76f   // 2.4^2
#define GRID 256
#define BLOCK 1024
#define MAXRPB 12    // ceil(3072/256)

typedef unsigned int u32;
typedef unsigned long long u64;

// ---------------------------------------------------------------------------
// Main: 256 blocks x 1024 threads. Each block REDUNDANTLY compacts the
// column/row lists into its own LDS (parallel across blocks, deterministic).
// Improvements over R7: is_ligand pre-balloted to an LDS bitmask (kills the
// dependent gather chain), chunked row ownership with ALL bond bitmasks
// loaded before ONE barrier (row loop is barrier-free; waves drift and
// self-hide latency).
// ---------------------------------------------------------------------------
__global__ __launch_bounds__(BLOCK) void plbl_main(
    const int* __restrict__ is_ligand,
    const int* __restrict__ token_bonds,
    const int* __restrict__ tokmap,
    const int* __restrict__ crd,
    const float* __restrict__ X,
    const float* __restrict__ Xgt,
    double* __restrict__ part_sum,
    u32* __restrict__ part_cnt)
{
    const int t = threadIdx.x;
    const int lane = t & 63;
    const int wv = t >> 6;

    __shared__ u64 s_lig[8];          // is_ligand bitmask (512 tokens)
    __shared__ u32 s_wtot[2][16];
    __shared__ u32 s_cnts[2];         // [0]=ncol [1]=nrow
    __shared__ u32 s_colmeta[3072];
    __shared__ u32 s_rowlist[3072];
    __shared__ u64 s_bond[MAXRPB][8];
    __shared__ double s_rsum[16];
    __shared__ u32 s_rcnt[16];

    // ---- ligand bitmask (one ballot pass, removes dependent gathers) -----
    if (t < NT) {
        const bool v = is_ligand[t] != 0;
        const u64 bal = __ballot(v);
        if (lane == 0) s_lig[wv] = bal;
    }
    __syncthreads();

    // ---------------- Phase A: in-LDS compaction --------------------------
    u32 cc = 0, rc = 0;
    u32 meta[3];
    bool cok[3], rok[3];
    #pragma unroll
    for (int k = 0; k < 3; k++) {
        const int a = t * 3 + k;
        const u32 tok = (u32)tokmap[a];
        const bool lig = (s_lig[tok >> 6] >> (tok & 63)) & 1ULL;
        const u32 m0 = crd[a] != 0;
        const u32 m1 = crd[L + a] != 0;
        const bool any = (m0 | m1) != 0u;
        meta[k] = (u32)a | (tok << 12) | (m0 << 21) | (m1 << 22);
        cok[k] = (!lig) && any;
        rok[k] = lig && any;
        cc += cok[k] ? 1u : 0u;
        rc += rok[k] ? 1u : 0u;
    }

    u32 ci = cc, ri = rc;
    #pragma unroll
    for (int o = 1; o < 64; o <<= 1) {
        u32 cv = __shfl_up(ci, o, 64);
        u32 rv = __shfl_up(ri, o, 64);
        if (lane >= o) { ci += cv; ri += rv; }
    }
    if (lane == 63) { s_wtot[0][wv] = ci; s_wtot[1][wv] = ri; }
    __syncthreads();

    if (wv == 0 && lane < 16) {
        const u32 c = s_wtot[0][lane];
        const u32 r = s_wtot[1][lane];
        u32 cs = c, rs = r;
        #pragma unroll
        for (int o = 1; o < 16; o <<= 1) {
            u32 cv = __shfl_up(cs, o, 64);
            u32 rv = __shfl_up(rs, o, 64);
            if (lane >= o) { cs += cv; rs += rv; }
        }
        s_wtot[0][lane] = cs - c;
        s_wtot[1][lane] = rs - r;
        if (lane == 15) { s_cnts[0] = cs; s_cnts[1] = rs; }
    }
    __syncthreads();

    u32 coff = s_wtot[0][wv] + (ci - cc);
    u32 roff = s_wtot[1][wv] + (ri - rc);
    #pragma unroll
    for (int k = 0; k < 3; k++) {
        if (cok[k]) s_colmeta[coff++] = meta[k];
        if (rok[k]) s_rowlist[roff++] = meta[k];
    }
    __syncthreads();

    const int ncol = (int)s_cnts[0];
    const int nrow = (int)s_cnts[1];

    // ---------------- Phase B: chunked rows, barrier-free row loop --------
    const int rpb = (nrow + GRID - 1) / GRID;
    const int r0 = blockIdx.x * rpb;
    const int r1 = (r0 + rpb < nrow) ? (r0 + rpb) : nrow;
    const int nr = (r1 > r0) ? (r1 - r0) : 0;

    // Load ALL owned bond rows into bitmasks, then ONE barrier.
    for (int r = 0; r < nr; r++) {
        const u32 rm = s_rowlist[r0 + r];
        const u32 ta1 = (rm >> 12) & 0x1FF;
        if (t < NT) {
            const bool bv = token_bonds[ta1 * NT + t] != 0;
            const u64 bal = __ballot(bv);
            if (lane == 0) s_bond[r][wv] = bal;
        }
    }
    __syncthreads();

    double acc = 0.0;
    u32 cnt = 0;

    for (int r = 0; r < nr; r++) {
        const u32 rm = s_rowlist[r0 + r];
        const int a1  = (int)(rm & 0xFFF);
        const u32 rbits = (rm >> 21) & 3u;   // m0 | m1<<1

        const float p0x = X[(0 * L + a1) * 3 + 0];
        const float p0y = X[(0 * L + a1) * 3 + 1];
        const float p0z = X[(0 * L + a1) * 3 + 2];
        const float p1x = X[(1 * L + a1) * 3 + 0];
        const float p1y = X[(1 * L + a1) * 3 + 1];
        const float p1z = X[(1 * L + a1) * 3 + 2];
        const float g0x = Xgt[(0 * L + a1) * 3 + 0];
        const float g0y = Xgt[(0 * L + a1) * 3 + 1];
        const float g0z = Xgt[(0 * L + a1) * 3 + 2];
        const float g1x = Xgt[(1 * L + a1) * 3 + 0];
        const float g1y = Xgt[(1 * L + a1) * 3 + 1];
        const float g1z = Xgt[(1 * L + a1) * 3 + 2];

        for (int j = t; j < ncol; j += BLOCK) {
            const u32 cm = s_colmeta[j];
            const int a2 = (int)(cm & 0xFFF);
            const u32 tok = (cm >> 12) & 0x1FF;
            const bool bond = (s_bond[r][tok >> 6] >> (tok & 63)) & 1ULL;

            const int b0 = 3 * a2;
            const int b1 = 3 * L + 3 * a2;
            const float vx0 = X[b0 + 0], vy0 = X[b0 + 1], vz0 = X[b0 + 2];
            const float vx1 = X[b1 + 0], vy1 = X[b1 + 1], vz1 = X[b1 + 2];
            const float wx0 = Xgt[b0 + 0], wy0 = Xgt[b0 + 1], wz0 = Xgt[b0 + 2];
            const float wx1 = Xgt[b1 + 0], wy1 = Xgt[b1 + 1], wz1 = Xgt[b1 + 2];

            // batch 0
            const float dgx0 = g0x - wx0, dgy0 = g0y - wy0, dgz0 = g0z - wz0;
            const float gt2_0 = dgx0 * dgx0 + dgy0 * dgy0 + dgz0 * dgz0;
            const float dpx0 = p0x - vx0, dpy0 = p0y - vy0, dpz0 = p0z - vz0;
            const float pr2_0 = dpx0 * dpx0 + dpy0 * dpy0 + dpz0 * dpz0;
            const float d0 = sqrtf(pr2_0) - sqrtf(gt2_0);
            const bool k0 = bond && (rbits & 1u) && ((cm >> 21) & 1u) && (gt2_0 < CUT2);
            // batch 1
            const float dgx1 = g1x - wx1, dgy1 = g1y - wy1, dgz1 = g1z - wz1;
            const float gt2_1 = dgx1 * dgx1 + dgy1 * dgy1 + dgz1 * dgz1;
            const float dpx1 = p1x - vx1, dpy1 = p1y - vy1, dpz1 = p1z - vz1;
            const float pr2_1 = dpx1 * dpx1 + dpy1 * dpy1 + dpz1 * dpz1;
            const float d1 = sqrtf(pr2_1) - sqrtf(gt2_1);
            const bool k1 = bond && (rbits & 2u) && ((cm >> 22) & 1u) && (gt2_1 < CUT2);

            const float e = (k0 ? d0 * d0 : 0.0f) + (k1 ? d1 * d1 : 0.0f);
            acc += (double)e;
            cnt += (k0 ? 1u : 0u) + (k1 ? 1u : 0u);
        }
    }

    // ---------------- Block reduction (16 waves) --------------------------
    #pragma unroll
    for (int o = 32; o > 0; o >>= 1) {
        acc += __shfl_down(acc, o, 64);
        cnt += __shfl_down(cnt, o, 64);
    }
    if (lane == 0) { s_rsum[wv] = acc; s_rcnt[wv] = cnt; }
    __syncthreads();
    if (t == 0) {
        double a = 0.0;
        u32 c = 0;
        #pragma unroll
        for (int i = 0; i < 16; i++) { a += s_rsum[i]; c += s_rcnt[i]; }
        part_sum[blockIdx.x] = a;
        part_cnt[blockIdx.x] = c;
    }
}

// ---------------------------------------------------------------------------
// Finalize: one block, deterministic reduction over GRID partials.
// ---------------------------------------------------------------------------
__global__ __launch_bounds__(256) void plbl_fin(
    const double* __restrict__ part_sum,
    const u32* __restrict__ part_cnt,
    float* __restrict__ out)
{
    const int t = threadIdx.x;
    const int lane = t & 63;
    const int wv = t >> 6;
    double a = part_sum[t];
    u32 c = part_cnt[t];
    #pragma unroll
    for (int o = 32; o > 0; o >>= 1) {
        a += __shfl_down(a, o, 64);
        c += __shfl_down(c, o, 64);
    }
    __shared__ double s_sum[4];
    __shared__ u32 s_cnt[4];
    if (lane == 0) { s_sum[wv] = a; s_cnt[wv] = c; }
    __syncthreads();
    if (t == 0) {
        const double sum = s_sum[0] + s_sum[1] + s_sum[2] + s_sum[3];
        const u32 cc = s_cnt[0] + s_cnt[1] + s_cnt[2] + s_cnt[3];
        const u32 n = cc ? cc : 1u;
        const float loss = (float)(sum / (double)n);
        out[0] = loss;
        out[1] = loss;
    }
}

extern "C" void kernel_launch(void* const* d_in, const int* in_sizes, int n_in,
                              void* d_out, int out_size, void* d_ws, size_t ws_size,
                              hipStream_t stream) {
    const int*   is_ligand   = (const int*)d_in[0];
    const int*   token_bonds = (const int*)d_in[1];
    const int*   tokmap      = (const int*)d_in[2];
    const int*   crd_mask    = (const int*)d_in[3];
    const float* X           = (const float*)d_in[4];
    const float* Xgt         = (const float*)d_in[5];
    float* out = (float*)d_out;

    char* w = (char*)d_ws;
    double* part_sum = (double*)(w + 0);
    u32*    part_cnt = (u32*)(w + 8 * GRID);

    plbl_main<<<GRID, BLOCK, 0, stream>>>(is_ligand, token_bonds, tokmap,
                                          crd_mask, X, Xgt,
                                          part_sum, part_cnt);
    plbl_fin<<<1, 256, 0, stream>>>(part_sum, part_cnt, out);
}

// Round 9
// 16.661 us; speedup vs baseline: 2.1574x; 1.1195x over previous
//
#include <hip/hip_runtime.h>

#define L 3072
#define NT 512
#define CUT2 5.76f   // 2.4^2
#define GRID 256
#define BLOCK 1024
#define MAXRPB 12    // ceil(3072/256)

typedef unsigned int u32;
typedef unsigned long long u64;

// ---------------------------------------------------------------------------
// Main: 256 blocks x 1024 threads (1 block/CU). Each block redundantly
// compacts col/row lists into LDS (parallel, deterministic). Phase B is
// LOOP-INVERTED vs R8: columns outer (coords loaded into registers ONCE),
// rows inner (row coords from LDS broadcast, bond bit from LDS bitmask).
// Global gathers per thread drop ~5x; inner loop is VALU+LDS only.
// ---------------------------------------------------------------------------
__global__ __launch_bounds__(BLOCK) void plbl_main(
    const int* __restrict__ is_ligand,
    const int* __restrict__ token_bonds,
    const int* __restrict__ tokmap,
    const int* __restrict__ crd,
    const float* __restrict__ X,
    const float* __restrict__ Xgt,
    double* __restrict__ part_sum,
    u32* __restrict__ part_cnt)
{
    const int t = threadIdx.x;
    const int lane = t & 63;
    const int wv = t >> 6;

    __shared__ u64 s_lig[8];           // is_ligand bitmask (512 tokens)
    __shared__ u32 s_wtot[2][16];
    __shared__ u32 s_cnts[2];          // [0]=ncol [1]=nrow
    __shared__ u32 s_colmeta[3072];
    __shared__ u32 s_rowlist[3072];
    __shared__ u64 s_bond[MAXRPB][8];
    __shared__ __align__(16) float s_rowc[MAXRPB][12];
    __shared__ u32 s_rbits[MAXRPB];
    __shared__ double s_rsum[16];
    __shared__ u32 s_rcnt[16];

    // ---- ligand bitmask ---------------------------------------------------
    if (t < NT) {
        const bool v = is_ligand[t] != 0;
        const u64 bal = __ballot(v);
        if (lane == 0) s_lig[wv] = bal;
    }
    __syncthreads();

    // ---------------- Phase A: in-LDS compaction --------------------------
    u32 cc = 0, rc = 0;
    u32 meta[3];
    bool cok[3], rok[3];
    #pragma unroll
    for (int k = 0; k < 3; k++) {
        const int a = t * 3 + k;
        const u32 tok = (u32)tokmap[a];
        const bool lig = (s_lig[tok >> 6] >> (tok & 63)) & 1ULL;
        const u32 m0 = crd[a] != 0;
        const u32 m1 = crd[L + a] != 0;
        const bool any = (m0 | m1) != 0u;
        meta[k] = (u32)a | (tok << 12) | (m0 << 21) | (m1 << 22);
        cok[k] = (!lig) && any;
        rok[k] = lig && any;
        cc += cok[k] ? 1u : 0u;
        rc += rok[k] ? 1u : 0u;
    }

    u32 ci = cc, ri = rc;
    #pragma unroll
    for (int o = 1; o < 64; o <<= 1) {
        u32 cv = __shfl_up(ci, o, 64);
        u32 rv = __shfl_up(ri, o, 64);
        if (lane >= o) { ci += cv; ri += rv; }
    }
    if (lane == 63) { s_wtot[0][wv] = ci; s_wtot[1][wv] = ri; }
    __syncthreads();

    if (wv == 0 && lane < 16) {
        const u32 c = s_wtot[0][lane];
        const u32 r = s_wtot[1][lane];
        u32 cs = c, rs = r;
        #pragma unroll
        for (int o = 1; o < 16; o <<= 1) {
            u32 cv = __shfl_up(cs, o, 64);
            u32 rv = __shfl_up(rs, o, 64);
            if (lane >= o) { cs += cv; rs += rv; }
        }
        s_wtot[0][lane] = cs - c;
        s_wtot[1][lane] = rs - r;
        if (lane == 15) { s_cnts[0] = cs; s_cnts[1] = rs; }
    }
    __syncthreads();

    u32 coff = s_wtot[0][wv] + (ci - cc);
    u32 roff = s_wtot[1][wv] + (ri - rc);
    #pragma unroll
    for (int k = 0; k < 3; k++) {
        if (cok[k]) s_colmeta[coff++] = meta[k];
        if (rok[k]) s_rowlist[roff++] = meta[k];
    }
    __syncthreads();

    const int ncol = (int)s_cnts[0];
    const int nrow = (int)s_cnts[1];

    // ---------------- Phase B staging: bond masks + row coords ------------
    const int rpb = (nrow + GRID - 1) / GRID;
    const int r0 = blockIdx.x * rpb;
    const int r1 = (r0 + rpb < nrow) ? (r0 + rpb) : nrow;
    const int nr = (r1 > r0) ? (r1 - r0) : 0;

    for (int r = 0; r < nr; r++) {
        const u32 rm = s_rowlist[r0 + r];
        const u32 ta1 = (rm >> 12) & 0x1FF;
        if (t < NT) {
            const bool bv = token_bonds[ta1 * NT + t] != 0;
            const u64 bal = __ballot(bv);
            if (lane == 0) s_bond[r][wv] = bal;
        }
    }
    if (t < nr * 12) {
        const int r = t / 12, c = t % 12;
        const u32 rm = s_rowlist[r0 + r];
        const int a1 = (int)(rm & 0xFFF);
        const int batch = (c % 6) / 3;
        const int axis  = c % 3;
        const float* src = (c < 6) ? X : Xgt;
        s_rowc[r][c] = src[(batch * L + a1) * 3 + axis];
    }
    if (t < nr) s_rbits[t] = (s_rowlist[r0 + t] >> 21) & 3u;
    __syncthreads();

    // ---------------- Phase B: columns outer (regs), rows inner -----------
    double acc = 0.0;
    u32 cnt = 0;

    for (int j = t; j < ncol; j += BLOCK) {
        const u32 cm = s_colmeta[j];
        const int a2 = (int)(cm & 0xFFF);
        const u32 tok = (cm >> 12) & 0x1FF;
        const u32 cbits = (cm >> 21) & 3u;
        const u32 bhi = tok >> 6;
        const u64 bsel = 1ULL << (tok & 63);

        const int b0 = 3 * a2;
        const int b1 = 3 * L + 3 * a2;
        const float vx0 = X[b0 + 0], vy0 = X[b0 + 1], vz0 = X[b0 + 2];
        const float vx1 = X[b1 + 0], vy1 = X[b1 + 1], vz1 = X[b1 + 2];
        const float wx0 = Xgt[b0 + 0], wy0 = Xgt[b0 + 1], wz0 = Xgt[b0 + 2];
        const float wx1 = Xgt[b1 + 0], wy1 = Xgt[b1 + 1], wz1 = Xgt[b1 + 2];

        for (int r = 0; r < nr; r++) {
            const bool bond = (s_bond[r][bhi] & bsel) != 0ULL;
            const u32 mb = s_rbits[r] & cbits;

            const float p0x = s_rowc[r][0], p0y = s_rowc[r][1], p0z = s_rowc[r][2];
            const float p1x = s_rowc[r][3], p1y = s_rowc[r][4], p1z = s_rowc[r][5];
            const float g0x = s_rowc[r][6], g0y = s_rowc[r][7], g0z = s_rowc[r][8];
            const float g1x = s_rowc[r][9], g1y = s_rowc[r][10], g1z = s_rowc[r][11];

            // batch 0
            const float dgx0 = g0x - wx0, dgy0 = g0y - wy0, dgz0 = g0z - wz0;
            const float gt2_0 = dgx0 * dgx0 + dgy0 * dgy0 + dgz0 * dgz0;
            const float dpx0 = p0x - vx0, dpy0 = p0y - vy0, dpz0 = p0z - vz0;
            const float pr2_0 = dpx0 * dpx0 + dpy0 * dpy0 + dpz0 * dpz0;
            const float d0 = sqrtf(pr2_0) - sqrtf(gt2_0);
            const bool k0 = bond && (mb & 1u) && (gt2_0 < CUT2);
            // batch 1
            const float dgx1 = g1x - wx1, dgy1 = g1y - wy1, dgz1 = g1z - wz1;
            const float gt2_1 = dgx1 * dgx1 + dgy1 * dgy1 + dgz1 * dgz1;
            const float dpx1 = p1x - vx1, dpy1 = p1y - vy1, dpz1 = p1z - vz1;
            const float pr2_1 = dpx1 * dpx1 + dpy1 * dpy1 + dpz1 * dpz1;
            const float d1 = sqrtf(pr2_1) - sqrtf(gt2_1);
            const bool k1 = bond && (mb & 2u) && (gt2_1 < CUT2);

            const float e = (k0 ? d0 * d0 : 0.0f) + (k1 ? d1 * d1 : 0.0f);
            acc += (double)e;
            cnt += (k0 ? 1u : 0u) + (k1 ? 1u : 0u);
        }
    }

    // ---------------- Block reduction (16 waves) --------------------------
    #pragma unroll
    for (int o = 32; o > 0; o >>= 1) {
        acc += __shfl_down(acc, o, 64);
        cnt += __shfl_down(cnt, o, 64);
    }
    if (lane == 0) { s_rsum[wv] = acc; s_rcnt[wv] = cnt; }
    __syncthreads();
    if (t == 0) {
        double a = 0.0;
        u32 c = 0;
        #pragma unroll
        for (int i = 0; i < 16; i++) { a += s_rsum[i]; c += s_rcnt[i]; }
        part_sum[blockIdx.x] = a;
        part_cnt[blockIdx.x] = c;
    }
}

// ---------------------------------------------------------------------------
// Finalize: one block, deterministic reduction over GRID partials.
// ---------------------------------------------------------------------------
__global__ __launch_bounds__(256) void plbl_fin(
    const double* __restrict__ part_sum,
    const u32* __restrict__ part_cnt,
    float* __restrict__ out)
{
    const int t = threadIdx.x;
    const int lane = t & 63;
    const int wv = t >> 6;
    double a = part_sum[t];
    u32 c = part_cnt[t];
    #pragma unroll
    for (int o = 32; o > 0; o >>= 1) {
        a += __shfl_down(a, o, 64);
        c += __shfl_down(c, o, 64);
    }
    __shared__ double s_sum[4];
    __shared__ u32 s_cnt[4];
    if (lane == 0) { s_sum[wv] = a; s_cnt[wv] = c; }
    __syncthreads();
    if (t == 0) {
        const double sum = s_sum[0] + s_sum[1] + s_sum[2] + s_sum[3];
        const u32 cc = s_cnt[0] + s_cnt[1] + s_cnt[2] + s_cnt[3];
        const u32 n = cc ? cc : 1u;
        const float loss = (float)(sum / (double)n);
        out[0] = loss;
        out[1] = loss;
    }
}

extern "C" void kernel_launch(void* const* d_in, const int* in_sizes, int n_in,
                              void* d_out, int out_size, void* d_ws, size_t ws_size,
                              hipStream_t stream) {
    const int*   is_ligand   = (const int*)d_in[0];
    const int*   token_bonds = (const int*)d_in[1];
    const int*   tokmap      = (const int*)d_in[2];
    const int*   crd_mask    = (const int*)d_in[3];
    const float* X           = (const float*)d_in[4];
    const float* Xgt         = (const float*)d_in[5];
    float* out = (float*)d_out;

    char* w = (char*)d_ws;
    double* part_sum = (double*)(w + 0);
    u32*    part_cnt = (u32*)(w + 8 * GRID);

    plbl_main<<<GRID, BLOCK, 0, stream>>>(is_ligand, token_bonds, tokmap,
                                          crd_mask, X, Xgt,
                                          part_sum, part_cnt);
    plbl_fin<<<1, 256, 0, stream>>>(part_sum, part_cnt, out);
}